// Round 1
// baseline (172.928 us; speedup 1.0000x reference)
//
#include <hip/hip_runtime.h>

// Conv2d: N=256, C=3, H=W=224, 5x5 filter, stride 1, pad 2, 1 output channel, + bias.
// out[n,y,x] = sum_{c,ky,kx} x[n,c,y+ky-2,x+kx-2] * w[c*25+ky*5+kx] + b
// Memory-bound (206 MB @ 6.3 TB/s ~= 33 us floor). Register-tiled direct conv:
// each thread computes a 4x4 output tile (12 loads/output vs 75 naive).

namespace {

constexpr int Hc = 224, Wc = 224, Cc = 3;
constexpr int TX = 4, TY = 4;            // per-thread output tile
constexpr int BDX = 16, BDY = 8;         // block dims (128 threads = 2 waves)
constexpr int TILE_X = BDX * TX;         // 64
constexpr int TILE_Y = BDY * TY;         // 32

template <bool GUARD>
__device__ __forceinline__ void conv_tile(const float* __restrict__ xn,
                                          const float* __restrict__ wl,
                                          float bias,
                                          float* __restrict__ outn,
                                          int x0, int y0) {
  float acc[TY][TX];
#pragma unroll
  for (int i = 0; i < TY; ++i)
#pragma unroll
    for (int j = 0; j < TX; ++j) acc[i][j] = 0.0f;

#pragma unroll
  for (int c = 0; c < Cc; ++c) {
    // Per-channel 5x5 weights; wave-uniform loads (broadcast / scalarizable).
    float wc[25];
#pragma unroll
    for (int i = 0; i < 25; ++i) wc[i] = wl[c * 25 + i];

    const float* xc = xn + c * (Hc * Wc);

#pragma unroll
    for (int iy = 0; iy < TY + 4; ++iy) {   // 8 input rows feed 4 output rows
      const int yi = y0 - 2 + iy;
      float r[TX + 4];                      // 8-wide sliding row segment
      if (!GUARD) {
        const float* row = xc + yi * Wc + (x0 - 2);
#pragma unroll
        for (int j = 0; j < TX + 4; ++j) r[j] = row[j];
      } else {
        const bool yok = (yi >= 0) && (yi < Hc);
        const float* row = xc + yi * Wc;
#pragma unroll
        for (int j = 0; j < TX + 4; ++j) {
          const int xi = x0 - 2 + j;
          r[j] = (yok && xi >= 0 && xi < Wc) ? row[xi] : 0.0f;
        }
      }
      // Input row iy contributes to output row oy = iy - ky for ky in [0,5).
#pragma unroll
      for (int ky = 0; ky < 5; ++ky) {
        const int oy = iy - ky;
        if (oy < 0 || oy >= TY) continue;   // resolved at compile time (unrolled)
#pragma unroll
        for (int ox = 0; ox < TX; ++ox) {
#pragma unroll
          for (int kx = 0; kx < 5; ++kx) {
            acc[oy][ox] = fmaf(r[ox + kx], wc[ky * 5 + kx], acc[oy][ox]);
          }
        }
      }
    }
  }

#pragma unroll
  for (int oy = 0; oy < TY; ++oy) {
    const int y = y0 + oy;
    if (GUARD && y >= Hc) continue;
    float* orow = outn + y * Wc;
#pragma unroll
    for (int ox = 0; ox < TX; ++ox) {
      const int x = x0 + ox;
      if (GUARD && x >= Wc) continue;
      orow[x] = acc[oy][ox] + bias;         // 4 consecutive stores -> dwordx4
    }
  }
}

__global__ __launch_bounds__(BDX * BDY) void conv5x5_k(
    const float* __restrict__ x, const float* __restrict__ wl,
    const float* __restrict__ b, float* __restrict__ out) {
  const int n = blockIdx.z;
  const int bx0 = blockIdx.x * TILE_X;
  const int by0 = blockIdx.y * TILE_Y;
  const int x0 = bx0 + threadIdx.x * TX;
  const int y0 = by0 + threadIdx.y * TY;

  const float bias = b[0];
  const float* xn = x + (size_t)n * (Cc * Hc * Wc);
  float* outn = out + (size_t)n * (Hc * Wc);

  // Interior block: halo fully inside image AND all outputs valid.
  const bool interior = (bx0 >= 2) && (bx0 + TILE_X + 2 <= Wc) &&
                        (by0 >= 2) && (by0 + TILE_Y + 2 <= Hc);
  if (interior) {
    conv_tile<false>(xn, wl, bias, outn, x0, y0);
  } else {
    conv_tile<true>(xn, wl, bias, outn, x0, y0);
  }
}

}  // namespace

extern "C" void kernel_launch(void* const* d_in, const int* in_sizes, int n_in,
                              void* d_out, int out_size, void* d_ws, size_t ws_size,
                              hipStream_t stream) {
  const float* x  = (const float*)d_in[0];   // [N,3,224,224] f32
  const float* wl = (const float*)d_in[1];   // [1,75] f32
  const float* b  = (const float*)d_in[2];   // [1] f32
  float* out = (float*)d_out;                // [N,224,224] f32

  const int N = out_size / (Hc * Wc);        // 256

  dim3 block(BDX, BDY, 1);
  dim3 grid((Wc + TILE_X - 1) / TILE_X,      // 4
            (Hc + TILE_Y - 1) / TILE_Y,      // 7
            N);                              // 256
  conv5x5_k<<<grid, block, 0, stream>>>(x, wl, b, out);
}

// Round 2
// 168.976 us; speedup vs baseline: 1.0234x; 1.0234x over previous
//
#include <hip/hip_runtime.h>

// Conv2d 5x5, C=3, 1 output channel, stride 1, pad 2, N=256, H=W=224, + bias.
// Latency-oriented rewrite: rolling-accumulator column walker.
//   - thread owns a float2-wide output column, walks SY=16 rows
//   - 5-deep register accumulator ring (acc0..acc4), one output row retires/step
//   - per step: 9 independent aligned 8B loads (3ch x 3 float2), 150 FMAs
//   - software pipeline: prefetch row yi+1 while accumulating row yi
//   - loads/output = 3 floats (12 B) -> L1/L2 traffic tiny; HBM fetch ~1.3x ideal
// Occupancy: __launch_bounds__(256,6) caps VGPR at ~85 -> 6 waves/SIMD;
// grid 1568 blocks x 4 waves = 6.1 waves/SIMD of work.

namespace {

constexpr int Hc = 224, Wc = 224, Cc = 3;
constexpr int HW = Hc * Wc;
constexpr int CHW = Cc * HW;
constexpr int TXv = 2;              // outputs per thread in x (float2)
constexpr int NCOL = Wc / TXv;      // 112
constexpr int SY = 16;              // strip height per thread
constexpr int NSTRIP = Hc / SY;     // 14
constexpr int BLK = 256;

// Load one input row (3 channels x 3 aligned float2) or zeros if row invalid.
// dst is a [Cc][3] float2 array; all indices compile-time (full unroll).
#define LOADROW(yi, dst)                                                      \
  do {                                                                        \
    if ((yi) >= 0 && (yi) < Hc) {                                             \
      const float* p_ = xb + (size_t)(yi) * Wc;                               \
      _Pragma("unroll") for (int c_ = 0; c_ < Cc; ++c_) {                     \
        const float* pc_ = p_ + c_ * HW;                                      \
        dst[c_][0] = *(const float2*)(pc_ + dA);                              \
        dst[c_][1] = *(const float2*)(pc_);                                   \
        dst[c_][2] = *(const float2*)(pc_ + dC);                              \
      }                                                                       \
    } else {                                                                  \
      _Pragma("unroll") for (int c_ = 0; c_ < Cc; ++c_) {                     \
        dst[c_][0] = make_float2(0.f, 0.f);                                   \
        dst[c_][1] = make_float2(0.f, 0.f);                                   \
        dst[c_][2] = make_float2(0.f, 0.f);                                   \
      }                                                                       \
    }                                                                         \
  } while (0)

// Accumulate one input row into the 5-deep ring. acc_k's output row gets
// tap ky = 4-k from this input row.
#define ACCUM(buf)                                                            \
  do {                                                                        \
    _Pragma("unroll") for (int c_ = 0; c_ < Cc; ++c_) {                       \
      float win[6];                                                           \
      win[0] = lo ? 0.f : buf[c_][0].x;                                       \
      win[1] = lo ? 0.f : buf[c_][0].y;                                       \
      win[2] = buf[c_][1].x;                                                  \
      win[3] = buf[c_][1].y;                                                  \
      win[4] = hi ? 0.f : buf[c_][2].x;                                       \
      win[5] = hi ? 0.f : buf[c_][2].y;                                       \
      _Pragma("unroll") for (int kx_ = 0; kx_ < 5; ++kx_) {                   \
        acc0.x = fmaf(win[kx_], w[c_][4][kx_], acc0.x);                       \
        acc0.y = fmaf(win[kx_ + 1], w[c_][4][kx_], acc0.y);                   \
        acc1.x = fmaf(win[kx_], w[c_][3][kx_], acc1.x);                       \
        acc1.y = fmaf(win[kx_ + 1], w[c_][3][kx_], acc1.y);                   \
        acc2.x = fmaf(win[kx_], w[c_][2][kx_], acc2.x);                       \
        acc2.y = fmaf(win[kx_ + 1], w[c_][2][kx_], acc2.y);                   \
        acc3.x = fmaf(win[kx_], w[c_][1][kx_], acc3.x);                       \
        acc3.y = fmaf(win[kx_ + 1], w[c_][1][kx_], acc3.y);                   \
        acc4.x = fmaf(win[kx_], w[c_][0][kx_], acc4.x);                       \
        acc4.y = fmaf(win[kx_ + 1], w[c_][0][kx_], acc4.y);                   \
      }                                                                       \
    }                                                                         \
  } while (0)

__global__ __launch_bounds__(BLK, 6) void conv5x5_roll(
    const float* __restrict__ x, const float* __restrict__ wl,
    const float* __restrict__ bptr, float* __restrict__ out) {
  const int t = blockIdx.x * BLK + threadIdx.x;
  // decode: col fastest (coalescing), then strip, then n. 112*14*256 threads.
  const int col = t % NCOL;
  const int rest = t / NCOL;
  const int strip = rest % NSTRIP;
  const int n = rest / NSTRIP;

  const int x0 = col * TXv;
  const int y0 = strip * SY;
  const bool lo = (x0 == 0);            // left image edge lane
  const bool hi = (x0 == Wc - TXv);     // right image edge lane

  // Weights: wave-uniform loads -> SGPRs (s_load). 75 + bias.
  float w[Cc][5][5];
#pragma unroll
  for (int c = 0; c < Cc; ++c)
#pragma unroll
    for (int i = 0; i < 25; ++i) w[c][i / 5][i % 5] = wl[c * 25 + i];
  const float bias = bptr[0];

  const float* xb = x + (size_t)n * CHW + x0;
  float* ob = out + (size_t)n * HW + x0;

  // Aligned 8B loads at x0-2 / x0 / x0+2. Edge lanes redirect the fully-
  // masked load inward (values zeroed in ACCUM) -> zero OOB accesses.
  const int dA = lo ? 0 : -2;
  const int dC = hi ? 0 : 2;

  float2 cur[Cc][3], nxt[Cc][3];
  float2 acc0 = {0.f, 0.f}, acc1 = {0.f, 0.f}, acc2 = {0.f, 0.f},
         acc3 = {0.f, 0.f}, acc4 = {0.f, 0.f};

  LOADROW(y0 - 2, cur);

#pragma unroll 2
  for (int yi = y0 - 2; yi < y0 + SY + 2; ++yi) {
    LOADROW(yi + 1, nxt);   // prefetch next row while computing current
    ACCUM(cur);
    if (yi >= y0 + 2) {     // output row yi-2 complete
      float2 o;
      o.x = acc0.x + bias;
      o.y = acc0.y + bias;
      *(float2*)(ob + (size_t)(yi - 2) * Wc) = o;
    }
    acc0 = acc1; acc1 = acc2; acc2 = acc3; acc3 = acc4;
    acc4 = make_float2(0.f, 0.f);
#pragma unroll
    for (int c = 0; c < Cc; ++c) {
      cur[c][0] = nxt[c][0];
      cur[c][1] = nxt[c][1];
      cur[c][2] = nxt[c][2];
    }
  }
}

}  // namespace

extern "C" void kernel_launch(void* const* d_in, const int* in_sizes, int n_in,
                              void* d_out, int out_size, void* d_ws, size_t ws_size,
                              hipStream_t stream) {
  const float* x  = (const float*)d_in[0];   // [N,3,224,224] f32
  const float* wl = (const float*)d_in[1];   // [1,75] f32
  const float* b  = (const float*)d_in[2];   // [1] f32
  float* out = (float*)d_out;                // [N,224,224] f32

  const int N = out_size / HW;               // 256
  const int total = N * NSTRIP * NCOL;       // 401408
  const int nblk = total / BLK;              // 1568

  conv5x5_roll<<<nblk, BLK, 0, stream>>>(x, wl, b, out);
}